// Round 1
// baseline (2699.757 us; speedup 1.0000x reference)
//
#include <hip/hip_runtime.h>
#include <math.h>

// ---------- types ----------
typedef __bf16 bf16_t;
typedef __bf16 bf16x8 __attribute__((ext_vector_type(8)));
typedef __bf16 bf16x4 __attribute__((ext_vector_type(4)));
typedef float  f32x4  __attribute__((ext_vector_type(4)));

#define NN 8192     // mesh nodes
#define CB 64       // channels
#define NB 4        // batch
#define LROWS 32768 // NB*NN

__device__ __forceinline__ float gelu_f(float x) {
    return 0.5f * x * (1.0f + erff(x * 0.70710678118654752f));
}

__device__ __forceinline__ float wsum64(float v) {
#pragma unroll
    for (int m = 32; m; m >>= 1) v += __shfl_xor(v, m);
    return v;
}

__device__ __forceinline__ void async16(const void* g, void* l) {
    __builtin_amdgcn_global_load_lds(
        (const __attribute__((address_space(1))) unsigned int*)g,
        (__attribute__((address_space(3))) unsigned int*)l,
        16, 0, 0);
}

// ---------- adj fp32 -> bf16 + row sums ----------
__global__ __launch_bounds__(256) void k_adj_convert(const float* __restrict__ adj,
                                                     bf16_t* __restrict__ adjB,
                                                     float* __restrict__ rowsum) {
    int row = blockIdx.x;
    int t = threadIdx.x;
    const float* ar = adj + (size_t)row * NN;
    bf16_t* br = adjB + (size_t)row * NN;
    float s = 0.f;
#pragma unroll
    for (int v = 0; v < 8; ++v) {
        int i = (v * 256 + t) * 4;
        float4 f = *(const float4*)(ar + i);
        s += f.x + f.y + f.z + f.w;
        bf16x4 o;
        o[0] = (bf16_t)f.x; o[1] = (bf16_t)f.y; o[2] = (bf16_t)f.z; o[3] = (bf16_t)f.w;
        *(bf16x4*)(br + i) = o;
    }
    s = wsum64(s);
    __shared__ float w4[4];
    if ((t & 63) == 0) w4[t >> 6] = s;
    __syncthreads();
    if (t == 0) rowsum[row] = w4[0] + w4[1] + w4[2] + w4[3];
}

// ---------- initial h = (concat(x,mesh)@fc0+b)@fc01+b ----------
__global__ void k_init_h(const float* __restrict__ x, const float* __restrict__ mesh,
                         const float* __restrict__ fc0w, const float* __restrict__ fc0b,
                         const float* __restrict__ fc01w, const float* __restrict__ fc01b,
                         float* __restrict__ h) {
    int row = blockIdx.x;           // b*NN+n
    int n = row & (NN - 1);
    int c = threadIdx.x;
    float xin = x[row];
    float m0 = mesh[n * 3], m1 = mesh[n * 3 + 1], m2 = mesh[n * 3 + 2];
    float t = fc0b[c] + xin * fc0w[c] + m0 * fc0w[64 + c] + m1 * fc0w[128 + c] + m2 * fc0w[192 + c];
    __shared__ float tl[64];
    tl[c] = t;
    __syncthreads();
    float hv = fc01b[c];
    for (int k = 0; k < 64; ++k) hv += tl[k] * fc01w[k * 64 + c];
    h[(size_t)row * 64 + c] = hv;
}

// ---------- encoder pre: t_l = (gelu(mesh@p1+b)@p2+b)@g1+b  -> Vt (transposed bf16) ----------
__global__ void k_enc_pre(const float* __restrict__ mesh,
                          const float* __restrict__ p1w, const float* __restrict__ p1b,
                          const float* __restrict__ p2w, const float* __restrict__ p2b,
                          const float* __restrict__ g1w, const float* __restrict__ g1b,
                          bf16_t* __restrict__ Vt) {
    int idx = blockIdx.x;
    int l = idx >> 13, n = idx & (NN - 1);
    int c = threadIdx.x;
    float m0 = mesh[n * 3], m1 = mesh[n * 3 + 1], m2 = mesh[n * 3 + 2];
    float e1 = gelu_f(p1b[l * 64 + c] + m0 * p1w[(l * 3 + 0) * 64 + c]
                      + m1 * p1w[(l * 3 + 1) * 64 + c] + m2 * p1w[(l * 3 + 2) * 64 + c]);
    __shared__ float lds[64];
    lds[c] = e1;
    __syncthreads();
    float e2 = p2b[l * 64 + c];
    for (int k = 0; k < 64; ++k) e2 += lds[k] * p2w[(l * 64 + k) * 64 + c];
    __syncthreads();
    lds[c] = e2;
    __syncthreads();
    float tt = g1b[l * 64 + c];
    for (int k = 0; k < 64; ++k) tt += lds[k] * g1w[(l * 64 + k) * 64 + c];
    Vt[(size_t)(l * 64 + c) * NN + n] = (bf16_t)tt;
}

// ---------- encoder mid: t2_l = gelu(G)@g2+b -> Vt ----------
__global__ void k_enc_mid(const float* __restrict__ G,
                          const float* __restrict__ g2w, const float* __restrict__ g2b,
                          bf16_t* __restrict__ Vt) {
    int idx = blockIdx.x;
    int l = idx >> 13, n = idx & (NN - 1);
    int c = threadIdx.x;
    float e3 = gelu_f(G[(size_t)n * 256 + l * 64 + c]);
    __shared__ float lds[64];
    lds[c] = e3;
    __syncthreads();
    float t2 = g2b[l * 64 + c];
    for (int k = 0; k < 64; ++k) t2 += lds[k] * g2w[(l * 64 + k) * 64 + c];
    Vt[(size_t)(l * 64 + c) * NN + n] = (bf16_t)t2;
}

// ---------- geo partials: e5 = (e4@o1+b)@o2+b ; partial[m,k] = sum_rows INV[m,n]*e5[n,k] ----------
__global__ void k_geo_part(const float* __restrict__ G,
                           const float* __restrict__ o1w, const float* __restrict__ o1b,
                           const float* __restrict__ o2w, const float* __restrict__ o2b,
                           const float* __restrict__ INV,
                           float* __restrict__ partials) {
    int l = blockIdx.x >> 7, chunk = blockIdx.x & 127;
    int n0 = chunk * 64;
    int t = threadIdx.x; // 0..63
    __shared__ float e4L[64][65];
    for (int r = 0; r < 64; ++r) e4L[r][t] = G[(size_t)(n0 + r) * 256 + l * 64 + t];
    __syncthreads();
    float e5[6] = {0, 0, 0, 0, 0, 0};
    const float* o1wl = o1w + (size_t)l * 64 * 128;
    const float* o2wl = o2w + (size_t)l * 128 * 6;
    for (int j = 0; j < 128; ++j) {
        float a = o1b[l * 128 + j];
        for (int i = 0; i < 64; ++i) a += e4L[t][i] * o1wl[i * 128 + j];
#pragma unroll
        for (int k = 0; k < 6; ++k) e5[k] += a * o2wl[j * 6 + k];
    }
#pragma unroll
    for (int k = 0; k < 6; ++k) e5[k] += o2b[l * 6 + k];
    __shared__ float e5L[64][8];
#pragma unroll
    for (int k = 0; k < 6; ++k) e5L[t][k] = e5[k];
    __syncthreads();
    float p[6] = {0, 0, 0, 0, 0, 0};
    const float* ivr = INV + (size_t)t * NN + n0;
    for (int r = 0; r < 64; ++r) {
        float iv = ivr[r];
#pragma unroll
        for (int k = 0; k < 6; ++k) p[k] += iv * e5L[r][k];
    }
#pragma unroll
    for (int k = 0; k < 6; ++k) partials[(size_t)(((l * 128 + chunk) * 64) + t) * 6 + k] = p[k];
}

// ---------- geo reduce + softmax(axis=NK) ----------
__global__ void k_geo_final(const float* __restrict__ partials, float* __restrict__ geoT) {
    int l = blockIdx.x, m = threadIdx.x;
    float g[6] = {0, 0, 0, 0, 0, 0};
    for (int ch = 0; ch < 128; ++ch) {
#pragma unroll
        for (int k = 0; k < 6; ++k) g[k] += partials[(size_t)(((l * 128 + ch) * 64) + m) * 6 + k];
    }
    float mx = g[0];
#pragma unroll
    for (int k = 1; k < 6; ++k) mx = fmaxf(mx, g[k]);
    float s = 0.f;
#pragma unroll
    for (int k = 0; k < 6; ++k) { g[k] = expf(g[k] - mx); s += g[k]; }
    float inv = 1.f / s;
#pragma unroll
    for (int k = 0; k < 6; ++k) geoT[(size_t)(l * 64 + m) * 6 + k] = g[k] * inv;
}

// ---------- z = LN(h)*g+b -> Vt bf16 transposed ----------
__global__ void k_z(const float* __restrict__ h, const float* __restrict__ g,
                    const float* __restrict__ bb, bf16_t* __restrict__ Vt) {
    int row = blockIdx.x;
    int b = row >> 13, n = row & (NN - 1);
    int c = threadIdx.x;
    float v = h[(size_t)row * 64 + c];
    float s = wsum64(v), s2 = wsum64(v * v);
    float mean = s * (1.f / 64.f);
    float var = s2 * (1.f / 64.f) - mean * mean;
    float z = (v - mean) * rsqrtf(var + 1e-5f) * g[c] + bb[c];
    Vt[(size_t)(b * 64 + c) * NN + n] = (bf16_t)z;
}

// ---------- cm[b,i,m] = sum_n INV[m,n]*z[b,n,i]  (z read from Vt bf16) ----------
__global__ __launch_bounds__(256) void k_cm(const float* __restrict__ INV,
                                            const bf16_t* __restrict__ Vt,
                                            float* __restrict__ cm) {
    int wid = threadIdx.x >> 6, lane = threadIdx.x & 63;
    int task = blockIdx.x * 4 + wid; // 0..16383
    int m = task & 63, i = (task >> 6) & 63, b = task >> 12;
    const float* iv = INV + (size_t)m * NN;
    const bf16_t* zt = Vt + (size_t)(b * 64 + i) * NN;
    float acc = 0.f;
    for (int it = 0; it < 32; ++it) {
        int n0 = (it * 64 + lane) * 4;
        float4 v = *(const float4*)(iv + n0);
        bf16x4 z4 = *(const bf16x4*)(zt + n0);
        acc += v.x * (float)z4[0] + v.y * (float)z4[1] + v.z * (float)z4[2] + v.w * (float)z4[3];
    }
    acc = wsum64(acc);
    if (lane == 0) cm[((b * 64 + i) * 64) + m] = acc;
}

// ---------- w[i,o,m]=sum_k spec*geoT ; cg[b,o,m]=sum_i cm*w ----------
__global__ __launch_bounds__(256) void k_cg(const float* __restrict__ specw,
                                            const float* __restrict__ geoT,
                                            const float* __restrict__ cm,
                                            float* __restrict__ cg, int l) {
    int m = blockIdx.x;
    int t = threadIdx.x;
    __shared__ float wsm[4096]; // [i*64+o]
    float gt[6];
#pragma unroll
    for (int k = 0; k < 6; ++k) gt[k] = geoT[(size_t)(l * 64 + m) * 6 + k];
    const float* sw = specw + (size_t)l * 6 * 64 * 64 * 64 + m;
    for (int rep = 0; rep < 16; ++rep) {
        int e = rep * 256 + t;
        float a = 0.f;
#pragma unroll
        for (int k = 0; k < 6; ++k) a += sw[(size_t)k * 262144 + (size_t)e * 64] * gt[k];
        wsm[e] = a;
    }
    __syncthreads();
    int b = t >> 6, o = t & 63;
    float a = 0.f;
    for (int i = 0; i < 64; ++i) a += cm[((b * 64 + i) * 64) + m] * wsm[i * 64 + o];
    cg[((b * 64 + o) * 64) + m] = a;
}

// ---------- spatial mid: s=relu(adjz@W1 + rowsum*b1); y=s@W2+b2 -> Vt ----------
__global__ void k_spat_mid(const float* __restrict__ G,
                           const float* __restrict__ W1, const float* __restrict__ b1,
                           const float* __restrict__ W2, const float* __restrict__ b2,
                           const float* __restrict__ rowsum, bf16_t* __restrict__ Vt) {
    int row = blockIdx.x;
    int b = row >> 13, m = row & (NN - 1);
    int t = threadIdx.x; // 0..127
    __shared__ float az[64], sj[128];
    if (t < 64) az[t] = G[(size_t)m * 256 + b * 64 + t];
    __syncthreads();
    float a = rowsum[m] * b1[t];
    for (int i = 0; i < 64; ++i) a += az[i] * W1[i * 128 + t];
    sj[t] = fmaxf(a, 0.f);
    __syncthreads();
    if (t < 64) {
        float y = b2[t];
        for (int j = 0; j < 128; ++j) y += sj[j] * W2[j * 64 + t];
        Vt[(size_t)(b * 64 + t) * NN + m] = (bf16_t)y;
    }
}

// ---------- block epilogue: x1=MP@cg^T, LN, +x2+h, LN2, MLP, +h ----------
__global__ void k_blk_post(float* __restrict__ h, const float* __restrict__ G,
                           const float* __restrict__ cg, const float* __restrict__ MP,
                           const float* __restrict__ n1g, const float* __restrict__ n1b,
                           const float* __restrict__ l2g, const float* __restrict__ l2b,
                           const float* __restrict__ prew, const float* __restrict__ preb,
                           const float* __restrict__ postw, const float* __restrict__ postb) {
    int row = blockIdx.x;
    int b = row >> 13, n = row & (NN - 1);
    int c = threadIdx.x;
    __shared__ float mp[64], zz[64], mid[128];
    mp[c] = MP[(size_t)n * 64 + c];
    __syncthreads();
    float x1 = 0.f;
    const float* cgr = cg + ((b * 64 + c) * 64);
    for (int m = 0; m < 64; ++m) x1 += mp[m] * cgr[m];
    float s = wsum64(x1), s2 = wsum64(x1 * x1);
    float mean = s * (1.f / 64.f), var = s2 * (1.f / 64.f) - mean * mean;
    x1 = (x1 - mean) * rsqrtf(var + 1e-5f) * n1g[c] + n1b[c];
    float hv = x1 + G[(size_t)n * 256 + b * 64 + c] + h[(size_t)row * 64 + c];
    s = wsum64(hv); s2 = wsum64(hv * hv);
    mean = s * (1.f / 64.f); var = s2 * (1.f / 64.f) - mean * mean;
    float z2 = (hv - mean) * rsqrtf(var + 1e-5f) * l2g[c] + l2b[c];
    zz[c] = z2;
    __syncthreads();
    float m0 = preb[c], m1 = preb[c + 64];
    for (int k = 0; k < 64; ++k) {
        float zk = zz[k];
        m0 += zk * prew[k * 128 + c];
        m1 += zk * prew[k * 128 + c + 64];
    }
    mid[c] = gelu_f(m0);
    mid[c + 64] = gelu_f(m1);
    __syncthreads();
    float o = postb[c];
    for (int j = 0; j < 128; ++j) o += mid[j] * postw[j * 64 + c];
    h[(size_t)row * 64 + c] = hv + o;
}

// ---------- final head ----------
__global__ void k_head(const float* __restrict__ h,
                       const float* __restrict__ g, const float* __restrict__ bb,
                       const float* __restrict__ fc1w, const float* __restrict__ fc1b,
                       const float* __restrict__ fc2w, const float* __restrict__ fc2b,
                       float* __restrict__ out) {
    int row = blockIdx.x;
    int c = threadIdx.x;
    float v = h[(size_t)row * 64 + c];
    float s = wsum64(v), s2 = wsum64(v * v);
    float mean = s * (1.f / 64.f), var = s2 * (1.f / 64.f) - mean * mean;
    float zf = (v - mean) * rsqrtf(var + 1e-5f) * g[c] + bb[c];
    __shared__ float zz[64];
    zz[c] = zf;
    __syncthreads();
    float m0 = fc1b[c], m1 = fc1b[c + 64];
    for (int k = 0; k < 64; ++k) {
        float zk = zz[k];
        m0 += zk * fc1w[k * 128 + c];
        m1 += zk * fc1w[k * 128 + c + 64];
    }
    float p = gelu_f(m0) * fc2w[c] + gelu_f(m1) * fc2w[c + 64];
    p = wsum64(p);
    if (c == 0) out[row] = p + fc2b[0];
}

// ---------- bf16 GEMM: C[8192,256] = A[8192,8192] @ Bt^T (Bt is [256,8192]) ----------
__global__ __launch_bounds__(256) void gemm_bf16(const bf16_t* __restrict__ A,
                                                 const bf16_t* __restrict__ Bt,
                                                 float* __restrict__ C) {
    __shared__ __align__(16) char smem[2][24576]; // A-tile 16KB + B-tile 8KB per buffer
    const int tn = blockIdx.x & 3;
    const int tm = blockIdx.x >> 2;
    const int t = threadIdx.x;
    const int lane = t & 63, wid = t >> 6;
    const int wr = wid >> 1, wc = wid & 1;
    const int lrow = lane & 15, lk = lane >> 4;

    const bf16_t* Abase = A + (size_t)tm * 128 * NN;
    const bf16_t* Bbase = Bt + (size_t)tn * 64 * NN;

    f32x4 acc[4][2];
#pragma unroll
    for (int i = 0; i < 4; ++i) {
        acc[i][0] = f32x4{0.f, 0.f, 0.f, 0.f};
        acc[i][1] = f32x4{0.f, 0.f, 0.f, 0.f};
    }

    auto stage = [&](int bsel, int kt) {
        char* lb = smem[bsel];
        int k0 = kt * 64;
#pragma unroll
        for (int r = 0; r < 4; ++r) {
            int ci = t + r * 256;            // chunk id in A tile (16B chunks)
            int rw = ci >> 3, ch = ci & 7;
            int sch = ch ^ (rw & 7);         // inverse-swizzled source chunk
            async16(Abase + (size_t)rw * NN + k0 + sch * 8, lb + ci * 16);
        }
#pragma unroll
        for (int r = 0; r < 2; ++r) {
            int ci = t + r * 256;            // chunk id in B tile
            int rw = ci >> 3, ch = ci & 7;
            int sch = ch ^ (rw & 7);
            async16(Bbase + (size_t)rw * NN + k0 + sch * 8, lb + 16384 + ci * 16);
        }
    };

    stage(0, 0);
    __syncthreads();
    for (int kt = 0; kt < 128; ++kt) {
        int cur = kt & 1;
        if (kt + 1 < 128) stage(cur ^ 1, kt + 1);
        const char* lb = smem[cur];
#pragma unroll
        for (int kk = 0; kk < 2; ++kk) {
            bf16x8 av[4], bv[2];
#pragma unroll
            for (int i = 0; i < 4; ++i) {
                int R = wr * 64 + i * 16 + lrow;
                av[i] = *(const bf16x8*)(lb + R * 128 + (((kk * 4 + lk) ^ (R & 7)) << 4));
            }
#pragma unroll
            for (int j = 0; j < 2; ++j) {
                int Q = wc * 32 + j * 16 + lrow;
                bv[j] = *(const bf16x8*)(lb + 16384 + Q * 128 + (((kk * 4 + lk) ^ (Q & 7)) << 4));
            }
#pragma unroll
            for (int i = 0; i < 4; ++i)
#pragma unroll
                for (int j = 0; j < 2; ++j)
                    acc[i][j] = __builtin_amdgcn_mfma_f32_16x16x32_bf16(av[i], bv[j], acc[i][j], 0, 0, 0);
        }
        __syncthreads();
    }

    int row0 = tm * 128 + wr * 64;
    int col0 = tn * 64 + wc * 32;
#pragma unroll
    for (int i = 0; i < 4; ++i)
#pragma unroll
        for (int j = 0; j < 2; ++j)
#pragma unroll
            for (int r = 0; r < 4; ++r)
                C[(size_t)(row0 + i * 16 + lk * 4 + r) * 256 + col0 + j * 16 + lrow] = acc[i][j][r];
}

// =====================================================================

extern "C" void kernel_launch(void* const* d_in, const int* in_sizes, int n_in,
                              void* d_out, int out_size, void* d_ws, size_t ws_size,
                              hipStream_t stream) {
    const float* x     = (const float*)d_in[0];
    const float* MP    = (const float*)d_in[1];
    const float* INV   = (const float*)d_in[2];
    const float* mesh  = (const float*)d_in[3];
    const float* adj   = (const float*)d_in[4];
    const float* fc0w  = (const float*)d_in[5];
    const float* fc0b  = (const float*)d_in[6];
    const float* fc01w = (const float*)d_in[7];
    const float* fc01b = (const float*)d_in[8];
    const float* bln1g = (const float*)d_in[9];
    const float* bln1b = (const float*)d_in[10];
    const float* n1g   = (const float*)d_in[11];
    const float* n1b   = (const float*)d_in[12];
    const float* specw = (const float*)d_in[13];
    const float* p1w   = (const float*)d_in[14];
    const float* p1b   = (const float*)d_in[15];
    const float* p2w   = (const float*)d_in[16];
    const float* p2b   = (const float*)d_in[17];
    const float* g1w   = (const float*)d_in[18];
    const float* g1b   = (const float*)d_in[19];
    const float* g2w   = (const float*)d_in[20];
    const float* g2b   = (const float*)d_in[21];
    const float* o1w   = (const float*)d_in[22];
    const float* o1b   = (const float*)d_in[23];
    const float* o2w   = (const float*)d_in[24];
    const float* o2b   = (const float*)d_in[25];
    const float* sg1w  = (const float*)d_in[26];
    const float* sg1b  = (const float*)d_in[27];
    const float* sg2w  = (const float*)d_in[28];
    const float* sg2b  = (const float*)d_in[29];
    const float* bln2g = (const float*)d_in[30];
    const float* bln2b = (const float*)d_in[31];
    const float* prew  = (const float*)d_in[32];
    const float* preb  = (const float*)d_in[33];
    const float* postw = (const float*)d_in[34];
    const float* postb = (const float*)d_in[35];
    const float* ln1g  = (const float*)d_in[36];
    const float* ln1b  = (const float*)d_in[37];
    const float* fc1w  = (const float*)d_in[38];
    const float* fc1b  = (const float*)d_in[39];
    const float* fc2w  = (const float*)d_in[40];
    const float* fc2b  = (const float*)d_in[41];
    float* out = (float*)d_out;

    char* ws = (char*)d_ws;
    bf16_t* adjB    = (bf16_t*)(ws);                       // 134,217,728 B
    bf16_t* Vt      = (bf16_t*)(ws + 134217728);           // 4,194,304 B  [256][8192] bf16
    float*  G       = (float*) (ws + 138412032);           // 8,388,608 B  [8192][256] f32
    float*  h       = (float*) (ws + 146800640);           // 8,388,608 B  [4][8192][64]
    float*  rowsum  = (float*) (ws + 155189248);           // 32,768 B
    float*  partials= (float*) (ws + 155222016);           // 786,432 B
    float*  geoT    = (float*) (ws + 156008448);           // 6,144 B
    float*  cm      = (float*) (ws + 156014592);           // 65,536 B
    float*  cg      = (float*) (ws + 156080128);           // 65,536 B

    // --- static prep ---
    k_adj_convert<<<NN, 256, 0, stream>>>(adj, adjB, rowsum);
    k_init_h<<<LROWS, 64, 0, stream>>>(x, mesh, fc0w, fc0b, fc01w, fc01b, h);

    // --- encoder for all 4 blocks (independent of h) ---
    k_enc_pre<<<4 * NN, 64, 0, stream>>>(mesh, p1w, p1b, p2w, p2b, g1w, g1b, Vt);
    gemm_bf16<<<256, 256, 0, stream>>>(adjB, Vt, G);
    k_enc_mid<<<4 * NN, 64, 0, stream>>>(G, g2w, g2b, Vt);
    gemm_bf16<<<256, 256, 0, stream>>>(adjB, Vt, G);
    k_geo_part<<<512, 64, 0, stream>>>(G, o1w, o1b, o2w, o2b, INV, partials);
    k_geo_final<<<4, 64, 0, stream>>>(partials, geoT);

    // --- 4 blocks ---
    for (int l = 0; l < 4; ++l) {
        k_z<<<LROWS, 64, 0, stream>>>(h, bln1g + l * 64, bln1b + l * 64, Vt);
        gemm_bf16<<<256, 256, 0, stream>>>(adjB, Vt, G);      // adj@z (and feeds spatial)
        k_cm<<<4096, 256, 0, stream>>>(INV, Vt, cm);          // INV@z from bf16 z
        k_cg<<<64, 256, 0, stream>>>(specw, geoT, cm, cg, l);
        k_spat_mid<<<LROWS, 128, 0, stream>>>(G, sg1w + l * 64 * 128, sg1b + l * 128,
                                              sg2w + l * 128 * 64, sg2b + l * 64, rowsum, Vt);
        gemm_bf16<<<256, 256, 0, stream>>>(adjB, Vt, G);      // x2 = adj@(s@W2+b2)
        k_blk_post<<<LROWS, 64, 0, stream>>>(h, G, cg, MP,
                                             n1g + l * 64, n1b + l * 64,
                                             bln2g + l * 64, bln2b + l * 64,
                                             prew + l * 64 * 128, preb + l * 128,
                                             postw + l * 128 * 64, postb + l * 64);
    }

    k_head<<<LROWS, 64, 0, stream>>>(h, ln1g, ln1b, fc1w, fc1b, fc2w, fc2b, out);
}

// Round 2
// 2297.996 us; speedup vs baseline: 1.1748x; 1.1748x over previous
//
#include <hip/hip_runtime.h>
#include <math.h>

// ---------- types ----------
typedef __bf16 bf16_t;
typedef __bf16 bf16x8 __attribute__((ext_vector_type(8)));
typedef __bf16 bf16x4 __attribute__((ext_vector_type(4)));
typedef float  f32x4  __attribute__((ext_vector_type(4)));

#define NN 8192      // mesh nodes
#define RA 8320      // A rows: 8192 adj + 64 INV + 64 zero pad
#define LROWS 32768  // NB*NN
#define GP1F 2129920 // RA*256 floats per split-K partial

__device__ __forceinline__ float gelu_f(float x) {
    return 0.5f * x * (1.0f + erff(x * 0.70710678118654752f));
}

__device__ __forceinline__ float wsum64(float v) {
#pragma unroll
    for (int m = 32; m; m >>= 1) v += __shfl_xor(v, m);
    return v;
}

// lane-broadcast via readlane (SGPR path, no LDS)
__device__ __forceinline__ float rl(float v, int k) {
    return __builtin_bit_cast(float, __builtin_amdgcn_readlane(__builtin_bit_cast(int, v), k));
}

__device__ __forceinline__ void async16(const void* g, void* l) {
    __builtin_amdgcn_global_load_lds(
        (const __attribute__((address_space(1))) unsigned int*)g,
        (__attribute__((address_space(3))) unsigned int*)l,
        16, 0, 0);
}

// ---------- adj fp32 -> bf16 + row sums ----------
__global__ __launch_bounds__(256) void k_adj_convert(const float* __restrict__ adj,
                                                     bf16_t* __restrict__ adjB,
                                                     float* __restrict__ rowsum) {
    int row = blockIdx.x;
    int t = threadIdx.x;
    const float* ar = adj + (size_t)row * NN;
    bf16_t* br = adjB + (size_t)row * NN;
    float s = 0.f;
#pragma unroll
    for (int v = 0; v < 8; ++v) {
        int i = (v * 256 + t) * 4;
        float4 f = *(const float4*)(ar + i);
        s += f.x + f.y + f.z + f.w;
        bf16x4 o;
        o[0] = (bf16_t)f.x; o[1] = (bf16_t)f.y; o[2] = (bf16_t)f.z; o[3] = (bf16_t)f.w;
        *(bf16x4*)(br + i) = o;
    }
    s = wsum64(s);
    __shared__ float w4[4];
    if ((t & 63) == 0) w4[t >> 6] = s;
    __syncthreads();
    if (t == 0) rowsum[row] = w4[0] + w4[1] + w4[2] + w4[3];
}

// ---------- INV rows 8192..8255 -> bf16 ; rows 8256..8319 zero ----------
__global__ __launch_bounds__(256) void k_inv_convert(const float* __restrict__ INV,
                                                     bf16_t* __restrict__ adjB) {
    int r = blockIdx.x; // 0..127
    int t = threadIdx.x;
    bf16_t* dst = adjB + (size_t)(NN + r) * NN;
    if (r < 64) {
        const float* src = INV + (size_t)r * NN;
#pragma unroll
        for (int v = 0; v < 8; ++v) {
            int i = (v * 256 + t) * 4;
            float4 f = *(const float4*)(src + i);
            bf16x4 o;
            o[0] = (bf16_t)f.x; o[1] = (bf16_t)f.y; o[2] = (bf16_t)f.z; o[3] = (bf16_t)f.w;
            *(bf16x4*)(dst + i) = o;
        }
    } else {
        bf16x4 zz; zz[0] = zz[1] = zz[2] = zz[3] = (bf16_t)0.f;
#pragma unroll
        for (int v = 0; v < 8; ++v) *(bf16x4*)(dst + (v * 256 + t) * 4) = zz;
    }
}

// ---------- initial h + z0 -> Vt ----------
__global__ __launch_bounds__(256) void k_init_h(const float* __restrict__ x, const float* __restrict__ mesh,
                         const float* __restrict__ fc0w, const float* __restrict__ fc0b,
                         const float* __restrict__ fc01w, const float* __restrict__ fc01b,
                         const float* __restrict__ zg, const float* __restrict__ zb,
                         float* __restrict__ h, bf16_t* __restrict__ Vt) {
    int w = blockIdx.x * 4 + (threadIdx.x >> 6); // row 0..32767
    int c = threadIdx.x & 63;
    int b = w >> 13, n = w & (NN - 1);
    float xin = x[w];
    float m0 = mesh[n * 3], m1 = mesh[n * 3 + 1], m2 = mesh[n * 3 + 2];
    float t = fc0b[c] + xin * fc0w[c] + m0 * fc0w[64 + c] + m1 * fc0w[128 + c] + m2 * fc0w[192 + c];
    float hv = fc01b[c];
#pragma unroll
    for (int k = 0; k < 64; ++k) hv += rl(t, k) * fc01w[k * 64 + c];
    h[(size_t)w * 64 + c] = hv;
    float s = wsum64(hv), s2 = wsum64(hv * hv);
    float mean = s * (1.f / 64.f), var = s2 * (1.f / 64.f) - mean * mean;
    float z = (hv - mean) * rsqrtf(var + 1e-5f) * zg[c] + zb[c];
    Vt[(size_t)(b * 64 + c) * NN + n] = (bf16_t)z;
}

// ---------- encoder pre ----------
__global__ __launch_bounds__(256) void k_enc_pre(const float* __restrict__ mesh,
                          const float* __restrict__ p1w, const float* __restrict__ p1b,
                          const float* __restrict__ p2w, const float* __restrict__ p2b,
                          const float* __restrict__ g1w, const float* __restrict__ g1b,
                          bf16_t* __restrict__ Vt) {
    int w = blockIdx.x * 4 + (threadIdx.x >> 6); // l*8192+n
    int l = w >> 13, n = w & (NN - 1);
    int c = threadIdx.x & 63;
    float m0 = mesh[n * 3], m1 = mesh[n * 3 + 1], m2 = mesh[n * 3 + 2];
    float e1 = gelu_f(p1b[l * 64 + c] + m0 * p1w[(l * 3 + 0) * 64 + c]
                      + m1 * p1w[(l * 3 + 1) * 64 + c] + m2 * p1w[(l * 3 + 2) * 64 + c]);
    float e2 = p2b[l * 64 + c];
#pragma unroll
    for (int k = 0; k < 64; ++k) e2 += rl(e1, k) * p2w[(l * 64 + k) * 64 + c];
    float tt = g1b[l * 64 + c];
#pragma unroll
    for (int k = 0; k < 64; ++k) tt += rl(e2, k) * g1w[(l * 64 + k) * 64 + c];
    Vt[(size_t)(l * 64 + c) * NN + n] = (bf16_t)tt;
}

// ---------- encoder mid ----------
__global__ __launch_bounds__(256) void k_enc_mid(const float* __restrict__ Gp,
                          const float* __restrict__ g2w, const float* __restrict__ g2b,
                          bf16_t* __restrict__ Vt) {
    int w = blockIdx.x * 4 + (threadIdx.x >> 6);
    int l = w >> 13, n = w & (NN - 1);
    int c = threadIdx.x & 63;
    size_t gi = (size_t)n * 256 + l * 64 + c;
    float e3 = gelu_f(Gp[gi] + Gp[gi + GP1F] + Gp[gi + 2 * (size_t)GP1F]);
    float t2 = g2b[l * 64 + c];
#pragma unroll
    for (int k = 0; k < 64; ++k) t2 += rl(e3, k) * g2w[(l * 64 + k) * 64 + c];
    Vt[(size_t)(l * 64 + c) * NN + n] = (bf16_t)t2;
}

// ---------- geo partials ----------
__global__ void k_geo_part(const float* __restrict__ Gp,
                           const float* __restrict__ o1w, const float* __restrict__ o1b,
                           const float* __restrict__ o2w, const float* __restrict__ o2b,
                           const float* __restrict__ INV,
                           float* __restrict__ partials) {
    int l = blockIdx.x >> 7, chunk = blockIdx.x & 127;
    int n0 = chunk * 64;
    int t = threadIdx.x; // 0..63
    __shared__ float e4L[64][65];
    for (int r = 0; r < 64; ++r) {
        size_t gi = (size_t)(n0 + r) * 256 + l * 64 + t;
        e4L[r][t] = Gp[gi] + Gp[gi + GP1F] + Gp[gi + 2 * (size_t)GP1F];
    }
    __syncthreads();
    float X[64];
#pragma unroll
    for (int i = 0; i < 64; ++i) X[i] = e4L[t][i];
    float e5[6] = {0, 0, 0, 0, 0, 0};
    const float* o1wl = o1w + (size_t)l * 64 * 128;
    const float* o2wl = o2w + (size_t)l * 128 * 6;
    for (int j = 0; j < 128; ++j) {
        float a = o1b[l * 128 + j];
#pragma unroll
        for (int i = 0; i < 64; ++i) a += X[i] * o1wl[i * 128 + j];
#pragma unroll
        for (int k = 0; k < 6; ++k) e5[k] += a * o2wl[j * 6 + k];
    }
#pragma unroll
    for (int k = 0; k < 6; ++k) e5[k] += o2b[l * 6 + k];
    __shared__ float e5L[64][8];
#pragma unroll
    for (int k = 0; k < 6; ++k) e5L[t][k] = e5[k];
    __syncthreads();
    float p[6] = {0, 0, 0, 0, 0, 0};
    const float* ivr = INV + (size_t)t * NN + n0;
    for (int r = 0; r < 64; ++r) {
        float iv = ivr[r];
#pragma unroll
        for (int k = 0; k < 6; ++k) p[k] += iv * e5L[r][k];
    }
#pragma unroll
    for (int k = 0; k < 6; ++k) partials[(size_t)(((l * 128 + chunk) * 64) + t) * 6 + k] = p[k];
}

// ---------- geo reduce + softmax ----------
__global__ void k_geo_final(const float* __restrict__ partials, float* __restrict__ geoT) {
    int l = blockIdx.x, m = threadIdx.x;
    float g[6] = {0, 0, 0, 0, 0, 0};
    for (int ch = 0; ch < 128; ++ch) {
#pragma unroll
        for (int k = 0; k < 6; ++k) g[k] += partials[(size_t)(((l * 128 + ch) * 64) + m) * 6 + k];
    }
    float mx = g[0];
#pragma unroll
    for (int k = 1; k < 6; ++k) mx = fmaxf(mx, g[k]);
    float s = 0.f;
#pragma unroll
    for (int k = 0; k < 6; ++k) { g[k] = expf(g[k] - mx); s += g[k]; }
    float inv = 1.f / s;
#pragma unroll
    for (int k = 0; k < 6; ++k) geoT[(size_t)(l * 64 + m) * 6 + k] = g[k] * inv;
}

// ---------- w[l][i][o][m] = sum_k spec[l][k][i][o][m]*geoT[l][m][k] ----------
__global__ __launch_bounds__(64) void k_w(const float* __restrict__ specw,
                                          const float* __restrict__ geoT,
                                          float* __restrict__ wAll) {
    int l = blockIdx.x >> 12, io = blockIdx.x & 4095;
    int m = threadIdx.x;
    float a = 0.f;
#pragma unroll
    for (int k = 0; k < 6; ++k)
        a += specw[(((size_t)l * 6 + k) * 4096 + io) * 64 + m] * geoT[(size_t)(l * 64 + m) * 6 + k];
    wAll[((size_t)l * 4096 + io) * 64 + m] = a;
}

// ---------- cmc[(b*64+i)*64+m] = sum_s Gp[s][8192+m][b*64+i] ----------
__global__ __launch_bounds__(256) void k_cmsum(const float* __restrict__ Gp, float* __restrict__ cmc) {
    int bi = blockIdx.x * 4 + (threadIdx.x >> 6);
    int m = threadIdx.x & 63;
    size_t gi = (size_t)(NN + m) * 256 + bi;
    cmc[bi * 64 + m] = Gp[gi] + Gp[gi + GP1F] + Gp[gi + 2 * (size_t)GP1F];
}

// ---------- cg[b][o][m] = sum_i cmc[b][i][m]*w[i][o][m] ----------
__global__ __launch_bounds__(256) void k_cg2(const float* __restrict__ cmc,
                                             const float* __restrict__ wl,
                                             float* __restrict__ cg) {
    int o = blockIdx.x;
    int b = threadIdx.x >> 6, m = threadIdx.x & 63;
    float acc = 0.f;
    for (int i = 0; i < 64; ++i)
        acc += cmc[(b * 64 + i) * 64 + m] * wl[((size_t)(i * 64 + o)) * 64 + m];
    cg[(b * 64 + o) * 64 + m] = acc;
}

// ---------- spatial mid ----------
__global__ __launch_bounds__(256) void k_spat_mid(const float* __restrict__ Gp,
                           const float* __restrict__ W1, const float* __restrict__ b1,
                           const float* __restrict__ W2, const float* __restrict__ b2,
                           const float* __restrict__ rowsum, bf16_t* __restrict__ Vt) {
    int w = blockIdx.x * 4 + (threadIdx.x >> 6);
    int b = w >> 13, m = w & (NN - 1);
    int c = threadIdx.x & 63;
    size_t gi = (size_t)m * 256 + b * 64 + c;
    float azv = Gp[gi] + Gp[gi + GP1F] + Gp[gi + 2 * (size_t)GP1F];
    float rs = rowsum[m];
    float a0 = rs * b1[c], a1 = rs * b1[c + 64];
#pragma unroll
    for (int k = 0; k < 64; ++k) {
        float xk = rl(azv, k);
        a0 += xk * W1[k * 128 + c];
        a1 += xk * W1[k * 128 + 64 + c];
    }
    a0 = fmaxf(a0, 0.f); a1 = fmaxf(a1, 0.f);
    float y = b2[c];
#pragma unroll
    for (int j = 0; j < 64; ++j) y += rl(a0, j) * W2[j * 64 + c];
#pragma unroll
    for (int j = 0; j < 64; ++j) y += rl(a1, j) * W2[(64 + j) * 64 + c];
    Vt[(size_t)(b * 64 + c) * NN + m] = (bf16_t)y;
}

// ---------- block epilogue (+ fused z_{l+1}) ----------
__global__ __launch_bounds__(256) void k_blk_post(float* __restrict__ h, const float* __restrict__ Gp,
                           const float* __restrict__ cg, const float* __restrict__ MP,
                           const float* __restrict__ n1g, const float* __restrict__ n1b,
                           const float* __restrict__ l2g, const float* __restrict__ l2b,
                           const float* __restrict__ prew, const float* __restrict__ preb,
                           const float* __restrict__ postw, const float* __restrict__ postb,
                           const float* __restrict__ zng, const float* __restrict__ znb,
                           bf16_t* __restrict__ Vt, int writeZ) {
    int w = blockIdx.x * 4 + (threadIdx.x >> 6);
    int b = w >> 13, n = w & (NN - 1);
    int c = threadIdx.x & 63;
    float mpv = MP[(size_t)n * 64 + c];
    const float* cgr = cg + ((size_t)(b * 64 + c)) * 64;
    f32x4 cgv[16];
#pragma unroll
    for (int q = 0; q < 16; ++q) cgv[q] = *(const f32x4*)(cgr + q * 4);
    float x1 = 0.f;
#pragma unroll
    for (int mi = 0; mi < 64; ++mi) x1 += rl(mpv, mi) * cgv[mi >> 2][mi & 3];
    float s = wsum64(x1), s2 = wsum64(x1 * x1);
    float mean = s * (1.f / 64.f), var = s2 * (1.f / 64.f) - mean * mean;
    x1 = (x1 - mean) * rsqrtf(var + 1e-5f) * n1g[c] + n1b[c];
    size_t gi = (size_t)n * 256 + b * 64 + c;
    float x2 = Gp[gi] + Gp[gi + GP1F] + Gp[gi + 2 * (size_t)GP1F];
    float hv = x1 + x2 + h[(size_t)w * 64 + c];
    s = wsum64(hv); s2 = wsum64(hv * hv);
    mean = s * (1.f / 64.f); var = s2 * (1.f / 64.f) - mean * mean;
    float z2 = (hv - mean) * rsqrtf(var + 1e-5f) * l2g[c] + l2b[c];
    float m0 = preb[c], m1 = preb[c + 64];
#pragma unroll
    for (int k = 0; k < 64; ++k) {
        float zk = rl(z2, k);
        m0 += zk * prew[k * 128 + c];
        m1 += zk * prew[k * 128 + 64 + c];
    }
    m0 = gelu_f(m0); m1 = gelu_f(m1);
    float o = postb[c];
#pragma unroll
    for (int j = 0; j < 64; ++j) o += rl(m0, j) * postw[j * 64 + c];
#pragma unroll
    for (int j = 0; j < 64; ++j) o += rl(m1, j) * postw[(64 + j) * 64 + c];
    hv += o;
    h[(size_t)w * 64 + c] = hv;
    if (writeZ) {
        s = wsum64(hv); s2 = wsum64(hv * hv);
        mean = s * (1.f / 64.f); var = s2 * (1.f / 64.f) - mean * mean;
        float z = (hv - mean) * rsqrtf(var + 1e-5f) * zng[c] + znb[c];
        Vt[(size_t)(b * 64 + c) * NN + n] = (bf16_t)z;
    }
}

// ---------- final head ----------
__global__ __launch_bounds__(256) void k_head(const float* __restrict__ h,
                       const float* __restrict__ g, const float* __restrict__ bb,
                       const float* __restrict__ fc1w, const float* __restrict__ fc1b,
                       const float* __restrict__ fc2w, const float* __restrict__ fc2b,
                       float* __restrict__ out) {
    int w = blockIdx.x * 4 + (threadIdx.x >> 6);
    int c = threadIdx.x & 63;
    float v = h[(size_t)w * 64 + c];
    float s = wsum64(v), s2 = wsum64(v * v);
    float mean = s * (1.f / 64.f), var = s2 * (1.f / 64.f) - mean * mean;
    float zf = (v - mean) * rsqrtf(var + 1e-5f) * g[c] + bb[c];
    float m0 = fc1b[c], m1 = fc1b[c + 64];
#pragma unroll
    for (int k = 0; k < 64; ++k) {
        float zk = rl(zf, k);
        m0 += zk * fc1w[k * 128 + c];
        m1 += zk * fc1w[k * 128 + 64 + c];
    }
    float p = gelu_f(m0) * fc2w[c] + gelu_f(m1) * fc2w[c + 64];
    p = wsum64(p);
    if (c == 0) out[w] = p + fc2b[0];
}

// ---------- bf16 GEMM split-K=3: Gp[s][8320][256] += A[8320,8192]@Bt^T ----------
__global__ __launch_bounds__(256) void gemm_bf16(const bf16_t* __restrict__ A,
                                                 const bf16_t* __restrict__ Bt,
                                                 float* __restrict__ Gp) {
    __shared__ __align__(16) char smem[2][24576]; // A 16KB + B 8KB per buffer
    const int bid = blockIdx.x;          // 0..779
    const int ks = bid / 260;
    const int r2 = bid % 260;
    const int tn = r2 & 3;
    const int tm = r2 >> 2;              // 0..64
    const int kt0 = (ks < 2) ? ks * 43 : 86;
    const int nkt = (ks < 2) ? 43 : 42;

    const int t = threadIdx.x;
    const int lane = t & 63, wid = t >> 6;
    const int wr = wid >> 1, wc = wid & 1;
    const int lrow = lane & 15, lk = lane >> 4;

    const bf16_t* Abase = A + (size_t)tm * 128 * NN;
    const bf16_t* Bbase = Bt + (size_t)tn * 64 * NN;

    f32x4 acc[4][2];
#pragma unroll
    for (int i = 0; i < 4; ++i) {
        acc[i][0] = f32x4{0.f, 0.f, 0.f, 0.f};
        acc[i][1] = f32x4{0.f, 0.f, 0.f, 0.f};
    }

    auto stage = [&](int bsel, int kt) {
        char* lb = smem[bsel];
        int k0 = kt * 64;
#pragma unroll
        for (int r = 0; r < 4; ++r) {
            int ci = t + r * 256;
            int rw = ci >> 3, ch = ci & 7;
            int sch = ch ^ (rw & 7);
            async16(Abase + (size_t)rw * NN + k0 + sch * 8, lb + ci * 16);
        }
#pragma unroll
        for (int r = 0; r < 2; ++r) {
            int ci = t + r * 256;
            int rw = ci >> 3, ch = ci & 7;
            int sch = ch ^ (rw & 7);
            async16(Bbase + (size_t)rw * NN + k0 + sch * 8, lb + 16384 + ci * 16);
        }
    };

    stage(0, kt0);
    __syncthreads();
    for (int it = 0; it < nkt; ++it) {
        int cur = it & 1;
        if (it + 1 < nkt) stage(cur ^ 1, kt0 + it + 1);
        const char* lb = smem[cur];
#pragma unroll
        for (int kk = 0; kk < 2; ++kk) {
            bf16x8 av[4], bv[2];
#pragma unroll
            for (int i = 0; i < 4; ++i) {
                int R = wr * 64 + i * 16 + lrow;
                av[i] = *(const bf16x8*)(lb + R * 128 + (((kk * 4 + lk) ^ (R & 7)) << 4));
            }
#pragma unroll
            for (int j = 0; j < 2; ++j) {
                int Q = wc * 32 + j * 16 + lrow;
                bv[j] = *(const bf16x8*)(lb + 16384 + Q * 128 + (((kk * 4 + lk) ^ (Q & 7)) << 4));
            }
#pragma unroll
            for (int i = 0; i < 4; ++i)
#pragma unroll
                for (int j = 0; j < 2; ++j)
                    acc[i][j] = __builtin_amdgcn_mfma_f32_16x16x32_bf16(av[i], bv[j], acc[i][j], 0, 0, 0);
        }
        __syncthreads();
    }

    float* Cs = Gp + (size_t)ks * GP1F;
    int row0 = tm * 128 + wr * 64;
    int col0 = tn * 64 + wc * 32;
#pragma unroll
    for (int i = 0; i < 4; ++i)
#pragma unroll
        for (int j = 0; j < 2; ++j)
#pragma unroll
            for (int r = 0; r < 4; ++r)
                Cs[(size_t)(row0 + i * 16 + lk * 4 + r) * 256 + col0 + j * 16 + lrow] = acc[i][j][r];
}

// =====================================================================

extern "C" void kernel_launch(void* const* d_in, const int* in_sizes, int n_in,
                              void* d_out, int out_size, void* d_ws, size_t ws_size,
                              hipStream_t stream) {
    const float* x     = (const float*)d_in[0];
    const float* MP    = (const float*)d_in[1];
    const float* INV   = (const float*)d_in[2];
    const float* mesh  = (const float*)d_in[3];
    const float* adj   = (const float*)d_in[4];
    const float* fc0w  = (const float*)d_in[5];
    const float* fc0b  = (const float*)d_in[6];
    const float* fc01w = (const float*)d_in[7];
    const float* fc01b = (const float*)d_in[8];
    const float* bln1g = (const float*)d_in[9];
    const float* bln1b = (const float*)d_in[10];
    const float* n1g   = (const float*)d_in[11];
    const float* n1b   = (const float*)d_in[12];
    const float* specw = (const float*)d_in[13];
    const float* p1w   = (const float*)d_in[14];
    const float* p1b   = (const float*)d_in[15];
    const float* p2w   = (const float*)d_in[16];
    const float* p2b   = (const float*)d_in[17];
    const float* g1w   = (const float*)d_in[18];
    const float* g1b   = (const float*)d_in[19];
    const float* g2w   = (const float*)d_in[20];
    const float* g2b   = (const float*)d_in[21];
    const float* o1w   = (const float*)d_in[22];
    const float* o1b   = (const float*)d_in[23];
    const float* o2w   = (const float*)d_in[24];
    const float* o2b   = (const float*)d_in[25];
    const float* sg1w  = (const float*)d_in[26];
    const float* sg1b  = (const float*)d_in[27];
    const float* sg2w  = (const float*)d_in[28];
    const float* sg2b  = (const float*)d_in[29];
    const float* bln2g = (const float*)d_in[30];
    const float* bln2b = (const float*)d_in[31];
    const float* prew  = (const float*)d_in[32];
    const float* preb  = (const float*)d_in[33];
    const float* postw = (const float*)d_in[34];
    const float* postb = (const float*)d_in[35];
    const float* ln1g  = (const float*)d_in[36];
    const float* ln1b  = (const float*)d_in[37];
    const float* fc1w  = (const float*)d_in[38];
    const float* fc1b  = (const float*)d_in[39];
    const float* fc2w  = (const float*)d_in[40];
    const float* fc2b  = (const float*)d_in[41];
    float* out = (float*)d_out;

    char* ws = (char*)d_ws;
    bf16_t* adjB    = (bf16_t*)(ws);                       // 136,314,880
    float*  Gp      = (float*) (ws + 136314880);           // 25,559,040 (3 splits)
    bf16_t* Vt      = (bf16_t*)(ws + 161873920);           // 4,194,304
    float*  h       = (float*) (ws + 166068224);           // 8,388,608
    float*  rowsum  = (float*) (ws + 174456832);           // 32,768
    float*  partials= (float*) (ws + 174489600);           // 786,432
    float*  geoT    = (float*) (ws + 175276032);           // 6,144
    float*  wAll    = (float*) (ws + 175282176);           // 4,194,304
    float*  cmc     = (float*) (ws + 179476480);           // 65,536
    float*  cg      = (float*) (ws + 179542016);           // 65,536

    // --- static prep ---
    k_adj_convert<<<NN, 256, 0, stream>>>(adj, adjB, rowsum);
    k_inv_convert<<<128, 256, 0, stream>>>(INV, adjB);

    // --- encoder for all 4 blocks ---
    k_enc_pre<<<8192, 256, 0, stream>>>(mesh, p1w, p1b, p2w, p2b, g1w, g1b, Vt);
    gemm_bf16<<<780, 256, 0, stream>>>(adjB, Vt, Gp);
    k_enc_mid<<<8192, 256, 0, stream>>>(Gp, g2w, g2b, Vt);
    gemm_bf16<<<780, 256, 0, stream>>>(adjB, Vt, Gp);
    k_geo_part<<<512, 64, 0, stream>>>(Gp, o1w, o1b, o2w, o2b, INV, partials);
    k_geo_final<<<4, 64, 0, stream>>>(partials, geoT);
    k_w<<<16384, 64, 0, stream>>>(specw, geoT, wAll);

    // --- h init (+z0) ---
    k_init_h<<<8192, 256, 0, stream>>>(x, mesh, fc0w, fc0b, fc01w, fc01b,
                                       bln1g, bln1b, h, Vt);

    // --- 4 blocks ---
    for (int l = 0; l < 4; ++l) {
        gemm_bf16<<<780, 256, 0, stream>>>(adjB, Vt, Gp);   // adj@z + INV@z
        k_cmsum<<<64, 256, 0, stream>>>(Gp, cmc);
        k_cg2<<<64, 256, 0, stream>>>(cmc, wAll + (size_t)l * 262144, cg);
        k_spat_mid<<<8192, 256, 0, stream>>>(Gp, sg1w + l * 64 * 128, sg1b + l * 128,
                                             sg2w + l * 128 * 64, sg2b + l * 64, rowsum, Vt);
        gemm_bf16<<<780, 256, 0, stream>>>(adjB, Vt, Gp);   // x2 = adj@y
        int ln = (l < 3) ? (l + 1) : 3;
        k_blk_post<<<8192, 256, 0, stream>>>(h, Gp, cg, MP,
                                             n1g + l * 64, n1b + l * 64,
                                             bln2g + l * 64, bln2b + l * 64,
                                             prew + l * 64 * 128, preb + l * 128,
                                             postw + l * 128 * 64, postb + l * 64,
                                             bln1g + ln * 64, bln1b + ln * 64,
                                             Vt, (l < 3) ? 1 : 0);
    }

    k_head<<<8192, 256, 0, stream>>>(h, ln1g, ln1b, fc1w, fc1b, fc2w, fc2b, out);
}